// Round 4
// baseline (750.615 us; speedup 1.0000x reference)
//
#include <hip/hip_runtime.h>

#define TPB 256
#define CHUNK 1024   // elements per scan block (256 threads x 4)
#define BSHIFT 6     // 64 nodes per bucket
#define BS (1 << BSHIFT)

// ---------------- degree count (int) ----------------

__global__ __launch_bounds__(TPB) void count_deg_kernel(const int* __restrict__ dst,
                                                        int* __restrict__ cnt, int e) {
    int i = blockIdx.x * TPB + threadIdx.x;
    if (i < e) atomicAdd(&cnt[dst[i]], 1);
}

__global__ __launch_bounds__(TPB) void dinv_kernel(const int* __restrict__ cnt,
                                                   float* __restrict__ dinv, int n) {
    int i = blockIdx.x * TPB + threadIdx.x;
    if (i < n) dinv[i] = rsqrtf((float)(cnt[i] + 1));  // +1 self-loop
}

// ---------------- two-level exclusive scan: counts -> row_ptr ----------------

__global__ __launch_bounds__(256) void scanA_kernel(const int* __restrict__ cnt,
                                                    int* __restrict__ row_ptr,
                                                    int* __restrict__ chunk_sums, int n) {
    __shared__ int ls[256];
    const int t    = threadIdx.x;
    const int base = blockIdx.x * CHUNK;
    const int idx  = base + t * 4;
    int4 v = make_int4(0, 0, 0, 0);
    if (idx + 3 < n) v = *(const int4*)(cnt + idx);
    else {
        if (idx + 0 < n) v.x = cnt[idx + 0];
        if (idx + 1 < n) v.y = cnt[idx + 1];
        if (idx + 2 < n) v.z = cnt[idx + 2];
        if (idx + 3 < n) v.w = cnt[idx + 3];
    }
    int s0 = v.x, s1 = s0 + v.y, s2 = s1 + v.z, s3 = s2 + v.w;
    ls[t] = s3;
    __syncthreads();
    for (int off = 1; off < 256; off <<= 1) {
        int xv = (t >= off) ? ls[t - off] : 0;
        __syncthreads();
        ls[t] += xv;
        __syncthreads();
    }
    int excl = (t == 0) ? 0 : ls[t - 1];
    if (idx + 0 < n) row_ptr[idx + 0] = excl;
    if (idx + 1 < n) row_ptr[idx + 1] = excl + s0;
    if (idx + 2 < n) row_ptr[idx + 2] = excl + s1;
    if (idx + 3 < n) row_ptr[idx + 3] = excl + s2;
    if (t == 255) chunk_sums[blockIdx.x] = ls[255];
}

__global__ __launch_bounds__(256) void scanB_kernel(int* __restrict__ chunk_sums, int nch) {
    __shared__ int ls[256];
    const int t = threadIdx.x;
    ls[t] = (t < nch) ? chunk_sums[t] : 0;
    __syncthreads();
    for (int off = 1; off < 256; off <<= 1) {
        int xv = (t >= off) ? ls[t - off] : 0;
        __syncthreads();
        ls[t] += xv;
        __syncthreads();
    }
    if (t < nch) chunk_sums[t] = (t == 0) ? 0 : ls[t - 1];  // exclusive
}

__global__ __launch_bounds__(256) void scanC_kernel(int* __restrict__ row_ptr,
                                                    const int* __restrict__ chunk_sums,
                                                    int n, int e_total) {
    const int base = blockIdx.x * CHUNK;
    const int off  = chunk_sums[blockIdx.x];
    for (int k = threadIdx.x; k < CHUNK; k += 256) {
        int i = base + k;
        if (i < n) row_ptr[i] += off;
    }
    if (blockIdx.x == 0 && threadIdx.x == 0) row_ptr[n] = e_total;
}

// ---------------- CSR build: two-pass bucket sort by dst ----------------

__global__ __launch_bounds__(TPB) void init_bucket_kernel(const int* __restrict__ row_ptr,
                                                          int* __restrict__ bucket_fill,
                                                          int nbk) {
    int i = blockIdx.x * TPB + threadIdx.x;
    if (i < nbk) bucket_fill[i] = row_ptr[i << BSHIFT];
}

// Pass B: scatter (src,dst) pairs into per-bucket contiguous regions.
// 1563 bucket counters -> low contention; writes fill dense 64B lines.
__global__ __launch_bounds__(TPB) void bucket_scatter_kernel(const int* __restrict__ src,
                                                             const int* __restrict__ dst,
                                                             int* __restrict__ bucket_fill,
                                                             int2* __restrict__ pairs, int e) {
    int i = blockIdx.x * TPB + threadIdx.x;
    if (i < e) {
        int d = dst[i];
        int q = atomicAdd(&bucket_fill[d >> BSHIFT], 1);
        pairs[q] = make_int2(src[i], d);
    }
}

// Pass C: one block per bucket; final per-node placement via LDS atomics,
// dense csr_src writes within the bucket's contiguous region.
__global__ __launch_bounds__(256) void bucket_sort_kernel(const int2* __restrict__ pairs,
                                                          const int* __restrict__ row_ptr,
                                                          int* __restrict__ csr_src, int n) {
    __shared__ int fill[BS];
    const int nb0 = blockIdx.x << BSHIFT;
    const int t   = threadIdx.x;
    if (t < BS) {
        int node = nb0 + t;
        fill[t] = (node < n) ? row_ptr[node] : 0;
    }
    const int nend = (nb0 + BS < n) ? nb0 + BS : n;
    const int r0 = row_ptr[nb0];
    const int r1 = row_ptr[nend];
    __syncthreads();
    for (int i = r0 + t; i < r1; i += 256) {
        int2 pr = pairs[i];
        int p = atomicAdd(&fill[pr.y - nb0], 1);
        csr_src[p] = pr.x;
    }
}

// ---------------- dense transform: HS = dinv[row] * (relu?)(X) @ W ----------------

template <int M, bool RELU>
__global__ __launch_bounds__(TPB) void gemm_kernel(const float* __restrict__ X,
                                                   const float* __restrict__ W,
                                                   const float* __restrict__ dinv,
                                                   float* __restrict__ H, int nrows) {
    constexpr int CG  = M / 4;        // col-groups of 4 (32 for M=128, 16 for M=64)
    constexpr int RG  = TPB / CG;     // row-groups per block (8 / 16)
    constexpr int R   = 4;            // rows per thread
    constexpr int RPB = RG * R;       // rows per block iter (32 / 64)
    __shared__ float Wl[128 * M];
    __shared__ float Xl[RPB * 128];

    for (int i = threadIdx.x; i < 128 * M / 4; i += TPB)
        ((float4*)Wl)[i] = ((const float4*)W)[i];

    const int cg = threadIdx.x % CG;
    const int rg = threadIdx.x / CG;

    for (long row0 = (long)blockIdx.x * RPB; row0 < nrows; row0 += (long)gridDim.x * RPB) {
        for (int f = threadIdx.x; f < RPB * 32; f += TPB) {
            int  r   = f >> 5;
            int  c4  = f & 31;
            long row = row0 + r;
            float4 v = make_float4(0.f, 0.f, 0.f, 0.f);
            if (row < nrows) v = ((const float4*)(X + row * 128))[c4];
            if (RELU) {
                v.x = fmaxf(v.x, 0.f); v.y = fmaxf(v.y, 0.f);
                v.z = fmaxf(v.z, 0.f); v.w = fmaxf(v.w, 0.f);
            }
            ((float4*)Xl)[f] = v;
        }
        __syncthreads();

        float4 acc[R];
#pragma unroll
        for (int r = 0; r < R; ++r) acc[r] = make_float4(0.f, 0.f, 0.f, 0.f);
        const float* xb = Xl + (rg * R) * 128;

#pragma unroll 8
        for (int k = 0; k < 128; ++k) {
            float4 wv = ((const float4*)Wl)[k * CG + cg];
#pragma unroll
            for (int r = 0; r < R; ++r) {
                float xv = xb[r * 128 + k];
                acc[r].x += xv * wv.x; acc[r].y += xv * wv.y;
                acc[r].z += xv * wv.z; acc[r].w += xv * wv.w;
            }
        }

#pragma unroll
        for (int r = 0; r < R; ++r) {
            long row = row0 + rg * R + r;
            if (row < nrows) {
                float dv = dinv[row];
                float4 o = make_float4(acc[r].x * dv, acc[r].y * dv,
                                       acc[r].z * dv, acc[r].w * dv);
                ((float4*)(H + row * M))[cg] = o;
            }
        }
        __syncthreads();
    }
}

// ---------------- pull aggregation: out[d] = b + dinv[d]*(hs[d] + sum hs[src]) ----------------

template <int M>
__global__ __launch_bounds__(TPB) void agg_pull_kernel(const float* __restrict__ hs,
                                                       const int* __restrict__ csr_src,
                                                       const int* __restrict__ row_ptr,
                                                       const float* __restrict__ dinv,
                                                       const float* __restrict__ bias,
                                                       float* __restrict__ out, int n) {
    const int node = blockIdx.x * (TPB / 64) + (threadIdx.x >> 6);
    const int lane = threadIdx.x & 63;
    if (node >= n) return;
    const int beg = row_ptr[node];
    const int end = row_ptr[node + 1];

    if constexpr (M == 128) {
        const float2* hp = (const float2*)hs;
        float2 a0 = hp[(long)node * 64 + lane];  // self-loop term
        float2 a1 = make_float2(0.f, 0.f);
        float2 a2 = make_float2(0.f, 0.f);
        float2 a3 = make_float2(0.f, 0.f);
        for (int base = beg; base < end; base += 64) {
            int m = end - base; if (m > 64) m = 64;
            int idx = (lane < m) ? csr_src[base + lane] : 0;  // coalesced index load
            int j = 0;
            for (; j + 3 < m; j += 4) {
                int s0 = __shfl(idx, j);
                int s1 = __shfl(idx, j + 1);
                int s2 = __shfl(idx, j + 2);
                int s3 = __shfl(idx, j + 3);
                float2 v0 = hp[(long)s0 * 64 + lane];
                float2 v1 = hp[(long)s1 * 64 + lane];
                float2 v2 = hp[(long)s2 * 64 + lane];
                float2 v3 = hp[(long)s3 * 64 + lane];
                a0.x += v0.x; a0.y += v0.y;
                a1.x += v1.x; a1.y += v1.y;
                a2.x += v2.x; a2.y += v2.y;
                a3.x += v3.x; a3.y += v3.y;
            }
            for (; j < m; ++j) {
                int s0 = __shfl(idx, j);
                float2 v0 = hp[(long)s0 * 64 + lane];
                a0.x += v0.x; a0.y += v0.y;
            }
        }
        float  di = dinv[node];
        float2 bv = ((const float2*)bias)[lane];
        float2 o;
        o.x = bv.x + di * ((a0.x + a1.x) + (a2.x + a3.x));
        o.y = bv.y + di * ((a0.y + a1.y) + (a2.y + a3.y));
        ((float2*)out)[(long)node * 64 + lane] = o;
    } else {  // M == 64
        float a0 = hs[(long)node * 64 + lane];
        float a1 = 0.f, a2 = 0.f, a3 = 0.f;
        for (int base = beg; base < end; base += 64) {
            int m = end - base; if (m > 64) m = 64;
            int idx = (lane < m) ? csr_src[base + lane] : 0;
            int j = 0;
            for (; j + 3 < m; j += 4) {
                int s0 = __shfl(idx, j);
                int s1 = __shfl(idx, j + 1);
                int s2 = __shfl(idx, j + 2);
                int s3 = __shfl(idx, j + 3);
                a0 += hs[(long)s0 * 64 + lane];
                a1 += hs[(long)s1 * 64 + lane];
                a2 += hs[(long)s2 * 64 + lane];
                a3 += hs[(long)s3 * 64 + lane];
            }
            for (; j < m; ++j) {
                int s0 = __shfl(idx, j);
                a0 += hs[(long)s0 * 64 + lane];
            }
        }
        float di = dinv[node];
        out[(long)node * 64 + lane] = bias[lane] + di * ((a0 + a1) + (a2 + a3));
    }
}

// ---------------- launcher ----------------

extern "C" void kernel_launch(void* const* d_in, const int* in_sizes, int n_in,
                              void* d_out, int out_size, void* d_ws, size_t ws_size,
                              hipStream_t stream) {
    const float* x  = (const float*)d_in[0];
    const int*   ei = (const int*)d_in[1];   // int32 on the wire
    const float* W1 = (const float*)d_in[2];
    const float* b1 = (const float*)d_in[3];
    const float* W2 = (const float*)d_in[4];
    const float* b2 = (const float*)d_in[5];
    float* out = (float*)d_out;

    const int N = in_sizes[0] / 128;   // 100000
    const int E = in_sizes[1] / 2;     // 1600000
    const int* srcv = ei;
    const int* dstv = ei + E;

    const int NCH = (N + CHUNK - 1) / CHUNK;          // 98 <= 256
    const int NBK = (N + BS - 1) >> BSHIFT;           // 1563 buckets

    // workspace layout
    char* p = (char*)d_ws;
    int*   cnt         = (int*)p;            p += ((size_t)N + 64) * 4;
    int*   row_ptr     = (int*)p;            p += ((size_t)N + 64) * 4;
    int*   chunk_sums  = (int*)p;            p += 1024;
    int*   bucket_fill = (int*)p;            p += ((size_t)NBK + 64) * 4;
    int*   csr_src     = (int*)p;            p += (size_t)E * 4;
    float* dinv        = (float*)p;          p += ((size_t)N + 64) * 4;
    float* h1          = (float*)p;          p += (size_t)N * 128 * 4;
    float* out1        = (float*)p;          /* p += N*128*4 */
    int2*  pairs       = (int2*)out1;        // alias: out1 dead until after CSR build
    float* h2          = h1;                 // h1 dead once out1 complete

    const int nb = (N + TPB - 1) / TPB;
    const int eb = (E + TPB - 1) / TPB;

    // ---- normalization + CSR build (bucket sort; reused by both layers) ----
    hipMemsetAsync(cnt, 0, (size_t)N * 4, stream);
    count_deg_kernel<<<eb, TPB, 0, stream>>>(dstv, cnt, E);
    dinv_kernel<<<nb, TPB, 0, stream>>>(cnt, dinv, N);
    scanA_kernel<<<NCH, 256, 0, stream>>>(cnt, row_ptr, chunk_sums, N);
    scanB_kernel<<<1, 256, 0, stream>>>(chunk_sums, NCH);
    scanC_kernel<<<NCH, 256, 0, stream>>>(row_ptr, chunk_sums, N, E);
    init_bucket_kernel<<<(NBK + TPB - 1) / TPB, TPB, 0, stream>>>(row_ptr, bucket_fill, NBK);
    bucket_scatter_kernel<<<eb, TPB, 0, stream>>>(srcv, dstv, bucket_fill, pairs, E);
    bucket_sort_kernel<<<NBK, 256, 0, stream>>>(pairs, row_ptr, csr_src, N);

    // ---- layer 1 ----
    gemm_kernel<128, false><<<(N + 31) / 32, TPB, 0, stream>>>(x, W1, dinv, h1, N);
    agg_pull_kernel<128><<<(N + 3) / 4, TPB, 0, stream>>>(h1, csr_src, row_ptr, dinv, b1, out1, N);

    // ---- layer 2 ----
    gemm_kernel<64, true><<<(N + 63) / 64, TPB, 0, stream>>>(out1, W2, dinv, h2, N);
    agg_pull_kernel<64><<<(N + 3) / 4, TPB, 0, stream>>>(h2, csr_src, row_ptr, dinv, b2, out, N);
}

// Round 5
// 558.996 us; speedup vs baseline: 1.3428x; 1.3428x over previous
//
#include <hip/hip_runtime.h>

#define TPB 256
#define CHUNK 1024   // elements per scan block (256 threads x 4)
#define EPB 4096     // edges per partition block
#define CSHIFT 8     // coarse bucket = 256 nodes

// ---------------- degree count (int) ----------------

__global__ __launch_bounds__(TPB) void count_deg_kernel(const int* __restrict__ dst,
                                                        int* __restrict__ cnt, int e) {
    int i = blockIdx.x * TPB + threadIdx.x;
    if (i < e) atomicAdd(&cnt[dst[i]], 1);
}

__global__ __launch_bounds__(TPB) void dinv_kernel(const int* __restrict__ cnt,
                                                   float* __restrict__ dinv, int n) {
    int i = blockIdx.x * TPB + threadIdx.x;
    if (i < n) dinv[i] = rsqrtf((float)(cnt[i] + 1));  // +1 self-loop
}

// ---------------- two-level exclusive scan (in-place safe) ----------------

__global__ __launch_bounds__(256) void scanA_kernel(const int* __restrict__ cnt,
                                                    int* __restrict__ row_ptr,
                                                    int* __restrict__ chunk_sums, int n) {
    __shared__ int ls[256];
    const int t    = threadIdx.x;
    const int base = blockIdx.x * CHUNK;
    const int idx  = base + t * 4;
    int4 v = make_int4(0, 0, 0, 0);
    if (idx + 3 < n) v = *(const int4*)(cnt + idx);
    else {
        if (idx + 0 < n) v.x = cnt[idx + 0];
        if (idx + 1 < n) v.y = cnt[idx + 1];
        if (idx + 2 < n) v.z = cnt[idx + 2];
        if (idx + 3 < n) v.w = cnt[idx + 3];
    }
    int s0 = v.x, s1 = s0 + v.y, s2 = s1 + v.z, s3 = s2 + v.w;
    ls[t] = s3;
    __syncthreads();
    for (int off = 1; off < 256; off <<= 1) {
        int xv = (t >= off) ? ls[t - off] : 0;
        __syncthreads();
        ls[t] += xv;
        __syncthreads();
    }
    int excl = (t == 0) ? 0 : ls[t - 1];
    if (idx + 0 < n) row_ptr[idx + 0] = excl;
    if (idx + 1 < n) row_ptr[idx + 1] = excl + s0;
    if (idx + 2 < n) row_ptr[idx + 2] = excl + s1;
    if (idx + 3 < n) row_ptr[idx + 3] = excl + s2;
    if (t == 255) chunk_sums[blockIdx.x] = ls[255];
}

__global__ __launch_bounds__(256) void scanB_kernel(int* __restrict__ chunk_sums, int nch) {
    __shared__ int ls[256];
    const int t = threadIdx.x;
    ls[t] = (t < nch) ? chunk_sums[t] : 0;
    __syncthreads();
    for (int off = 1; off < 256; off <<= 1) {
        int xv = (t >= off) ? ls[t - off] : 0;
        __syncthreads();
        ls[t] += xv;
        __syncthreads();
    }
    if (t < nch) chunk_sums[t] = (t == 0) ? 0 : ls[t - 1];  // exclusive
}

__global__ __launch_bounds__(256) void scanC_kernel(int* __restrict__ row_ptr,
                                                    const int* __restrict__ chunk_sums,
                                                    int n, int e_total) {
    const int base = blockIdx.x * CHUNK;
    const int off  = chunk_sums[blockIdx.x];
    for (int k = threadIdx.x; k < CHUNK; k += 256) {
        int i = base + k;
        if (i < n) row_ptr[i] += off;
    }
    if (blockIdx.x == 0 && threadIdx.x == 0) row_ptr[n] = e_total;
}

// ---------------- CSR build: deterministic counting partition ----------------
// Phase A: per-block histogram over coarse bins (dst>>8) -> hist[bin][block].

__global__ __launch_bounds__(256) void hist_kernel(const int* __restrict__ dst,
                                                   int* __restrict__ hist_g,
                                                   int e, int nbc, int nblk) {
    __shared__ int hs[512];
    const int t = threadIdx.x;
    for (int i = t; i < nbc; i += 256) hs[i] = 0;
    __syncthreads();
    const int e0  = blockIdx.x * EPB;
    const int lim = min(e0 + EPB, e);
    for (int i = e0 + t; i < lim; i += 256)
        atomicAdd(&hs[dst[i] >> CSHIFT], 1);
    __syncthreads();
    for (int b = t; b < nbc; b += 256)
        hist_g[b * nblk + blockIdx.x] = hs[b];
}

// Phase C: re-read edges, stage bin-ordered in LDS, write coalesced runs to
// exact precomputed positions. Zero global atomics.

__global__ __launch_bounds__(256) void partition_kernel(const int* __restrict__ src,
                                                        const int* __restrict__ dst,
                                                        const int* __restrict__ hist_scan,
                                                        int2* __restrict__ pairs,
                                                        int e, int nbc, int nblk) {
    __shared__ int  hs[512];
    __shared__ int  lscan[512];
    __shared__ int  lfill[512];
    __shared__ int  base_s[512];
    __shared__ int  ls[256];
    __shared__ int2 sp[EPB];   // 32 KB staging
    const int t = threadIdx.x;
    for (int i = t; i < nbc; i += 256) { hs[i] = 0; lfill[i] = 0; }
    __syncthreads();
    const int e0  = blockIdx.x * EPB;
    const int lim = min(e0 + EPB, e);
    for (int i = e0 + t; i < lim; i += 256)
        atomicAdd(&hs[dst[i] >> CSHIFT], 1);
    __syncthreads();
    // exclusive scan of hs[0..nbc) (2 elems/thread, padded to 512)
    int v0 = (2 * t     < nbc) ? hs[2 * t]     : 0;
    int v1 = (2 * t + 1 < nbc) ? hs[2 * t + 1] : 0;
    ls[t] = v0 + v1;
    __syncthreads();
    for (int off = 1; off < 256; off <<= 1) {
        int xv = (t >= off) ? ls[t - off] : 0;
        __syncthreads();
        ls[t] += xv;
        __syncthreads();
    }
    int excl = (t == 0) ? 0 : ls[t - 1];
    if (2 * t     < nbc) lscan[2 * t]     = excl;
    if (2 * t + 1 < nbc) lscan[2 * t + 1] = excl + v0;
    for (int b = t; b < nbc; b += 256) base_s[b] = hist_scan[b * nblk + blockIdx.x];
    __syncthreads();
    // stage bin-ordered
    for (int i = e0 + t; i < lim; i += 256) {
        int d = dst[i];
        int b = d >> CSHIFT;
        int r = atomicAdd(&lfill[b], 1);
        sp[lscan[b] + r] = make_int2(src[i], d);
    }
    __syncthreads();
    // write out: consecutive i in same bin -> consecutive dest (coalesced runs)
    const int cnt = lim - e0;
    for (int i = t; i < cnt; i += 256) {
        int2 pr = sp[i];
        int  b  = pr.y >> CSHIFT;
        pairs[base_s[b] + (i - lscan[b])] = pr;
    }
}

// Pass 2: one block per 256-node bucket; LDS per-node placement, dense
// csr_src writes within the bucket's L2-resident contiguous region.

__global__ __launch_bounds__(256) void bucket_sort_kernel(const int2* __restrict__ pairs,
                                                          const int* __restrict__ row_ptr,
                                                          int* __restrict__ csr_src, int n) {
    __shared__ int fill[256];
    const int nb0 = blockIdx.x << CSHIFT;
    const int t   = threadIdx.x;
    int node = nb0 + t;
    fill[t] = (node < n) ? row_ptr[node] : 0;
    const int nend = (nb0 + 256 < n) ? nb0 + 256 : n;
    const int r0 = row_ptr[nb0];
    const int r1 = row_ptr[nend];
    __syncthreads();
    for (int i = r0 + t; i < r1; i += 256) {
        int2 pr = pairs[i];
        int  p  = atomicAdd(&fill[pr.y - nb0], 1);
        csr_src[p] = pr.x;
    }
}

// ---------------- dense transform: HS = dinv[row] * (relu?)(X) @ W ----------------

template <int M, bool RELU>
__global__ __launch_bounds__(TPB) void gemm_kernel(const float* __restrict__ X,
                                                   const float* __restrict__ W,
                                                   const float* __restrict__ dinv,
                                                   float* __restrict__ H, int nrows) {
    constexpr int CG  = M / 4;
    constexpr int RG  = TPB / CG;
    constexpr int R   = 4;
    constexpr int RPB = RG * R;
    __shared__ float Wl[128 * M];
    __shared__ float Xl[RPB * 128];

    for (int i = threadIdx.x; i < 128 * M / 4; i += TPB)
        ((float4*)Wl)[i] = ((const float4*)W)[i];

    const int cg = threadIdx.x % CG;
    const int rg = threadIdx.x / CG;

    for (long row0 = (long)blockIdx.x * RPB; row0 < nrows; row0 += (long)gridDim.x * RPB) {
        for (int f = threadIdx.x; f < RPB * 32; f += TPB) {
            int  r   = f >> 5;
            int  c4  = f & 31;
            long row = row0 + r;
            float4 v = make_float4(0.f, 0.f, 0.f, 0.f);
            if (row < nrows) v = ((const float4*)(X + row * 128))[c4];
            if (RELU) {
                v.x = fmaxf(v.x, 0.f); v.y = fmaxf(v.y, 0.f);
                v.z = fmaxf(v.z, 0.f); v.w = fmaxf(v.w, 0.f);
            }
            ((float4*)Xl)[f] = v;
        }
        __syncthreads();

        float4 acc[R];
#pragma unroll
        for (int r = 0; r < R; ++r) acc[r] = make_float4(0.f, 0.f, 0.f, 0.f);
        const float* xb = Xl + (rg * R) * 128;

#pragma unroll 8
        for (int k = 0; k < 128; ++k) {
            float4 wv = ((const float4*)Wl)[k * CG + cg];
#pragma unroll
            for (int r = 0; r < R; ++r) {
                float xv = xb[r * 128 + k];
                acc[r].x += xv * wv.x; acc[r].y += xv * wv.y;
                acc[r].z += xv * wv.z; acc[r].w += xv * wv.w;
            }
        }

#pragma unroll
        for (int r = 0; r < R; ++r) {
            long row = row0 + rg * R + r;
            if (row < nrows) {
                float dv = dinv[row];
                float4 o = make_float4(acc[r].x * dv, acc[r].y * dv,
                                       acc[r].z * dv, acc[r].w * dv);
                ((float4*)(H + row * M))[cg] = o;
            }
        }
        __syncthreads();
    }
}

// ---------------- pull aggregation: out[d] = b + dinv[d]*(hs[d] + sum hs[src]) ----------------

template <int M>
__global__ __launch_bounds__(TPB) void agg_pull_kernel(const float* __restrict__ hs,
                                                       const int* __restrict__ csr_src,
                                                       const int* __restrict__ row_ptr,
                                                       const float* __restrict__ dinv,
                                                       const float* __restrict__ bias,
                                                       float* __restrict__ out, int n) {
    const int node = blockIdx.x * (TPB / 64) + (threadIdx.x >> 6);
    const int lane = threadIdx.x & 63;
    if (node >= n) return;
    const int beg = row_ptr[node];
    const int end = row_ptr[node + 1];

    if constexpr (M == 128) {
        const float2* hp = (const float2*)hs;
        float2 a0 = hp[(long)node * 64 + lane];  // self-loop term
        float2 a1 = make_float2(0.f, 0.f);
        float2 a2 = make_float2(0.f, 0.f);
        float2 a3 = make_float2(0.f, 0.f);
        for (int base = beg; base < end; base += 64) {
            int m = end - base; if (m > 64) m = 64;
            int idx = (lane < m) ? csr_src[base + lane] : 0;
            int j = 0;
            for (; j + 3 < m; j += 4) {
                int s0 = __shfl(idx, j);
                int s1 = __shfl(idx, j + 1);
                int s2 = __shfl(idx, j + 2);
                int s3 = __shfl(idx, j + 3);
                float2 v0 = hp[(long)s0 * 64 + lane];
                float2 v1 = hp[(long)s1 * 64 + lane];
                float2 v2 = hp[(long)s2 * 64 + lane];
                float2 v3 = hp[(long)s3 * 64 + lane];
                a0.x += v0.x; a0.y += v0.y;
                a1.x += v1.x; a1.y += v1.y;
                a2.x += v2.x; a2.y += v2.y;
                a3.x += v3.x; a3.y += v3.y;
            }
            for (; j < m; ++j) {
                int s0 = __shfl(idx, j);
                float2 v0 = hp[(long)s0 * 64 + lane];
                a0.x += v0.x; a0.y += v0.y;
            }
        }
        float  di = dinv[node];
        float2 bv = ((const float2*)bias)[lane];
        float2 o;
        o.x = bv.x + di * ((a0.x + a1.x) + (a2.x + a3.x));
        o.y = bv.y + di * ((a0.y + a1.y) + (a2.y + a3.y));
        ((float2*)out)[(long)node * 64 + lane] = o;
    } else {  // M == 64
        float a0 = hs[(long)node * 64 + lane];
        float a1 = 0.f, a2 = 0.f, a3 = 0.f;
        for (int base = beg; base < end; base += 64) {
            int m = end - base; if (m > 64) m = 64;
            int idx = (lane < m) ? csr_src[base + lane] : 0;
            int j = 0;
            for (; j + 3 < m; j += 4) {
                int s0 = __shfl(idx, j);
                int s1 = __shfl(idx, j + 1);
                int s2 = __shfl(idx, j + 2);
                int s3 = __shfl(idx, j + 3);
                a0 += hs[(long)s0 * 64 + lane];
                a1 += hs[(long)s1 * 64 + lane];
                a2 += hs[(long)s2 * 64 + lane];
                a3 += hs[(long)s3 * 64 + lane];
            }
            for (; j < m; ++j) {
                int s0 = __shfl(idx, j);
                a0 += hs[(long)s0 * 64 + lane];
            }
        }
        float di = dinv[node];
        out[(long)node * 64 + lane] = bias[lane] + di * ((a0 + a1) + (a2 + a3));
    }
}

// ---------------- launcher ----------------

extern "C" void kernel_launch(void* const* d_in, const int* in_sizes, int n_in,
                              void* d_out, int out_size, void* d_ws, size_t ws_size,
                              hipStream_t stream) {
    const float* x  = (const float*)d_in[0];
    const int*   ei = (const int*)d_in[1];   // int32 on the wire
    const float* W1 = (const float*)d_in[2];
    const float* b1 = (const float*)d_in[3];
    const float* W2 = (const float*)d_in[4];
    const float* b2 = (const float*)d_in[5];
    float* out = (float*)d_out;

    const int N = in_sizes[0] / 128;   // 100000
    const int E = in_sizes[1] / 2;     // 1600000
    const int* srcv = ei;
    const int* dstv = ei + E;

    const int NCH    = (N + CHUNK - 1) / CHUNK;       // 98
    const int NBC    = (N + 255) >> CSHIFT;           // 391 coarse buckets
    const int NBLK_E = (E + EPB - 1) / EPB;           // 391 edge blocks
    const int HLEN   = NBC * NBLK_E;                  // 152,881
    const int NCHH   = (HLEN + CHUNK - 1) / CHUNK;    // 150

    // workspace layout
    char* p = (char*)d_ws;
    int*   cnt        = (int*)p;            p += ((size_t)N + 64) * 4;
    int*   row_ptr    = (int*)p;            p += ((size_t)N + 64) * 4;
    int*   chunk_sums = (int*)p;            p += 1024;
    int*   hist       = (int*)p;            p += ((size_t)HLEN + 64) * 4;
    int*   csr_src    = (int*)p;            p += (size_t)E * 4;
    float* dinv       = (float*)p;          p += ((size_t)N + 64) * 4;
    float* h1         = (float*)p;          p += (size_t)N * 128 * 4;
    float* out1       = (float*)p;          /* p += N*128*4 */
    int2*  pairs      = (int2*)out1;        // alias: out1 dead until after CSR build
    float* h2         = h1;                 // h1 dead once out1 complete

    const int nb = (N + TPB - 1) / TPB;
    const int eb = (E + TPB - 1) / TPB;

    // ---- normalization + row_ptr ----
    hipMemsetAsync(cnt, 0, (size_t)N * 4, stream);
    count_deg_kernel<<<eb, TPB, 0, stream>>>(dstv, cnt, E);
    dinv_kernel<<<nb, TPB, 0, stream>>>(cnt, dinv, N);
    scanA_kernel<<<NCH, 256, 0, stream>>>(cnt, row_ptr, chunk_sums, N);
    scanB_kernel<<<1, 256, 0, stream>>>(chunk_sums, NCH);
    scanC_kernel<<<NCH, 256, 0, stream>>>(row_ptr, chunk_sums, N, E);

    // ---- CSR build: histogram -> scan -> partition -> bucket sort ----
    hist_kernel<<<NBLK_E, 256, 0, stream>>>(dstv, hist, E, NBC, NBLK_E);
    scanA_kernel<<<NCHH, 256, 0, stream>>>(hist, hist, chunk_sums, HLEN);  // in-place safe
    scanB_kernel<<<1, 256, 0, stream>>>(chunk_sums, NCHH);
    scanC_kernel<<<NCHH, 256, 0, stream>>>(hist, chunk_sums, HLEN, E);
    partition_kernel<<<NBLK_E, 256, 0, stream>>>(srcv, dstv, hist, pairs, E, NBC, NBLK_E);
    bucket_sort_kernel<<<NBC, 256, 0, stream>>>(pairs, row_ptr, csr_src, N);

    // ---- layer 1 ----
    gemm_kernel<128, false><<<(N + 31) / 32, TPB, 0, stream>>>(x, W1, dinv, h1, N);
    agg_pull_kernel<128><<<(N + 3) / 4, TPB, 0, stream>>>(h1, csr_src, row_ptr, dinv, b1, out1, N);

    // ---- layer 2 ----
    gemm_kernel<64, true><<<(N + 63) / 64, TPB, 0, stream>>>(out1, W2, dinv, h2, N);
    agg_pull_kernel<64><<<(N + 3) / 4, TPB, 0, stream>>>(h2, csr_src, row_ptr, dinv, b2, out, N);
}

// Round 7
// 476.721 us; speedup vs baseline: 1.5745x; 1.1726x over previous
//
#include <hip/hip_runtime.h>

#define TPB 256
#define CHUNK 1024   // elements per scan block (256 threads x 4)
#define EPB 4096     // edges per partition block
#define CSHIFT 8     // coarse bucket = 256 nodes

// ---------------- two-level exclusive scan (in-place safe) ----------------

__global__ __launch_bounds__(256) void scanA_kernel(const int* __restrict__ cnt,
                                                    int* __restrict__ row_ptr,
                                                    int* __restrict__ chunk_sums, int n) {
    __shared__ int ls[256];
    const int t    = threadIdx.x;
    const int base = blockIdx.x * CHUNK;
    const int idx  = base + t * 4;
    int4 v = make_int4(0, 0, 0, 0);
    if (idx + 3 < n) v = *(const int4*)(cnt + idx);
    else {
        if (idx + 0 < n) v.x = cnt[idx + 0];
        if (idx + 1 < n) v.y = cnt[idx + 1];
        if (idx + 2 < n) v.z = cnt[idx + 2];
        if (idx + 3 < n) v.w = cnt[idx + 3];
    }
    int s0 = v.x, s1 = s0 + v.y, s2 = s1 + v.z, s3 = s2 + v.w;
    ls[t] = s3;
    __syncthreads();
    for (int off = 1; off < 256; off <<= 1) {
        int xv = (t >= off) ? ls[t - off] : 0;
        __syncthreads();
        ls[t] += xv;
        __syncthreads();
    }
    int excl = (t == 0) ? 0 : ls[t - 1];
    if (idx + 0 < n) row_ptr[idx + 0] = excl;
    if (idx + 1 < n) row_ptr[idx + 1] = excl + s0;
    if (idx + 2 < n) row_ptr[idx + 2] = excl + s1;
    if (idx + 3 < n) row_ptr[idx + 3] = excl + s2;
    if (t == 255) chunk_sums[blockIdx.x] = ls[255];
}

__global__ __launch_bounds__(256) void scanB_kernel(int* __restrict__ chunk_sums, int nch) {
    __shared__ int ls[256];
    const int t = threadIdx.x;
    ls[t] = (t < nch) ? chunk_sums[t] : 0;
    __syncthreads();
    for (int off = 1; off < 256; off <<= 1) {
        int xv = (t >= off) ? ls[t - off] : 0;
        __syncthreads();
        ls[t] += xv;
        __syncthreads();
    }
    if (t < nch) chunk_sums[t] = (t == 0) ? 0 : ls[t - 1];  // exclusive
}

__global__ __launch_bounds__(256) void scanC_kernel(int* __restrict__ row_ptr,
                                                    const int* __restrict__ chunk_sums, int n) {
    const int base = blockIdx.x * CHUNK;
    const int off  = chunk_sums[blockIdx.x];
    for (int k = threadIdx.x; k < CHUNK; k += 256) {
        int i = base + k;
        if (i < n) row_ptr[i] += off;
    }
}

// ---------------- CSR build: deterministic counting partition ----------------

__global__ __launch_bounds__(256) void hist_kernel(const int* __restrict__ dst,
                                                   int* __restrict__ hist_g,
                                                   int e, int nbc, int nblk) {
    __shared__ int hs[512];
    const int t = threadIdx.x;
    for (int i = t; i < nbc; i += 256) hs[i] = 0;
    __syncthreads();
    const int e0  = blockIdx.x * EPB;
    const int lim = min(e0 + EPB, e);
    for (int i = e0 + t; i < lim; i += 256)
        atomicAdd(&hs[dst[i] >> CSHIFT], 1);
    __syncthreads();
    for (int b = t; b < nbc; b += 256)
        hist_g[b * nblk + blockIdx.x] = hs[b];
}

__global__ __launch_bounds__(256) void partition_kernel(const int* __restrict__ src,
                                                        const int* __restrict__ dst,
                                                        const int* __restrict__ hist_scan,
                                                        int2* __restrict__ pairs,
                                                        int e, int nbc, int nblk) {
    __shared__ int  hs[512];
    __shared__ int  lscan[512];
    __shared__ int  lfill[512];
    __shared__ int  base_s[512];
    __shared__ int  ls[256];
    __shared__ int2 sp[EPB];   // 32 KB staging
    const int t = threadIdx.x;
    for (int i = t; i < nbc; i += 256) { hs[i] = 0; lfill[i] = 0; }
    __syncthreads();
    const int e0  = blockIdx.x * EPB;
    const int lim = min(e0 + EPB, e);
    for (int i = e0 + t; i < lim; i += 256)
        atomicAdd(&hs[dst[i] >> CSHIFT], 1);
    __syncthreads();
    int v0 = (2 * t     < nbc) ? hs[2 * t]     : 0;
    int v1 = (2 * t + 1 < nbc) ? hs[2 * t + 1] : 0;
    ls[t] = v0 + v1;
    __syncthreads();
    for (int off = 1; off < 256; off <<= 1) {
        int xv = (t >= off) ? ls[t - off] : 0;
        __syncthreads();
        ls[t] += xv;
        __syncthreads();
    }
    int excl = (t == 0) ? 0 : ls[t - 1];
    if (2 * t     < nbc) lscan[2 * t]     = excl;
    if (2 * t + 1 < nbc) lscan[2 * t + 1] = excl + v0;
    for (int b = t; b < nbc; b += 256) base_s[b] = hist_scan[b * nblk + blockIdx.x];
    __syncthreads();
    for (int i = e0 + t; i < lim; i += 256) {
        int d = dst[i];
        int b = d >> CSHIFT;
        int r = atomicAdd(&lfill[b], 1);
        sp[lscan[b] + r] = make_int2(src[i], d);
    }
    __syncthreads();
    const int cnt = lim - e0;
    for (int i = t; i < cnt; i += 256) {
        int2 pr = sp[i];
        int  b  = pr.y >> CSHIFT;
        pairs[base_s[b] + (i - lscan[b])] = pr;
    }
}

// One block per 256-node bucket: per-node count + scan in LDS, then write
// row_ptr, dinv, and place csr_src. No global atomics anywhere.
__global__ __launch_bounds__(256) void bucket_finalize_kernel(const int2* __restrict__ pairs,
                                                              const int* __restrict__ hist_scan,
                                                              int* __restrict__ row_ptr,
                                                              float* __restrict__ dinv,
                                                              int* __restrict__ csr_src,
                                                              int n, int e, int nbc, int nblk) {
    __shared__ int cnt_s[256];
    __shared__ int fill[256];
    __shared__ int ls[256];
    const int b   = blockIdx.x;
    const int nb0 = b << CSHIFT;
    const int t   = threadIdx.x;
    const int r0  = hist_scan[b * nblk];                       // bucket start
    const int r1  = (b + 1 < nbc) ? hist_scan[(b + 1) * nblk] : e;
    cnt_s[t] = 0;
    __syncthreads();
    for (int i = r0 + t; i < r1; i += 256)
        atomicAdd(&cnt_s[pairs[i].y - nb0], 1);
    __syncthreads();
    int c = cnt_s[t];
    ls[t] = c;
    __syncthreads();
    for (int off = 1; off < 256; off <<= 1) {
        int xv = (t >= off) ? ls[t - off] : 0;
        __syncthreads();
        ls[t] += xv;
        __syncthreads();
    }
    int excl = (t == 0) ? 0 : ls[t - 1];
    int node = nb0 + t;
    if (node < n) {
        row_ptr[node] = r0 + excl;
        dinv[node]    = rsqrtf((float)(c + 1));   // +1 self-loop
    }
    fill[t] = r0 + excl;
    __syncthreads();
    for (int i = r0 + t; i < r1; i += 256) {
        int2 pr = pairs[i];
        int  p  = atomicAdd(&fill[pr.y - nb0], 1);
        csr_src[p] = pr.x;
    }
    if (b == 0 && t == 0) row_ptr[n] = e;
}

// ---------------- dense transform: HS = dinv[row] * (relu?)(X) @ W ----------------

template <int M, bool RELU>
__global__ __launch_bounds__(TPB) void gemm_kernel(const float* __restrict__ X,
                                                   const float* __restrict__ W,
                                                   const float* __restrict__ dinv,
                                                   float* __restrict__ H, int nrows) {
    constexpr int CG  = M / 4;
    constexpr int RG  = TPB / CG;
    constexpr int R   = 4;
    constexpr int RPB = RG * R;
    __shared__ float Wl[128 * M];
    __shared__ float Xl[RPB * 128];

    for (int i = threadIdx.x; i < 128 * M / 4; i += TPB)
        ((float4*)Wl)[i] = ((const float4*)W)[i];

    const int cg = threadIdx.x % CG;
    const int rg = threadIdx.x / CG;

    for (long row0 = (long)blockIdx.x * RPB; row0 < nrows; row0 += (long)gridDim.x * RPB) {
        for (int f = threadIdx.x; f < RPB * 32; f += TPB) {
            int  r   = f >> 5;
            int  c4  = f & 31;
            long row = row0 + r;
            float4 v = make_float4(0.f, 0.f, 0.f, 0.f);
            if (row < nrows) v = ((const float4*)(X + row * 128))[c4];
            if (RELU) {
                v.x = fmaxf(v.x, 0.f); v.y = fmaxf(v.y, 0.f);
                v.z = fmaxf(v.z, 0.f); v.w = fmaxf(v.w, 0.f);
            }
            ((float4*)Xl)[f] = v;
        }
        __syncthreads();

        float4 acc[R];
#pragma unroll
        for (int r = 0; r < R; ++r) acc[r] = make_float4(0.f, 0.f, 0.f, 0.f);
        const float* xb = Xl + (rg * R) * 128;

#pragma unroll 8
        for (int k = 0; k < 128; ++k) {
            float4 wv = ((const float4*)Wl)[k * CG + cg];
#pragma unroll
            for (int r = 0; r < R; ++r) {
                float xv = xb[r * 128 + k];
                acc[r].x += xv * wv.x; acc[r].y += xv * wv.y;
                acc[r].z += xv * wv.z; acc[r].w += xv * wv.w;
            }
        }

#pragma unroll
        for (int r = 0; r < R; ++r) {
            long row = row0 + rg * R + r;
            if (row < nrows) {
                float dv = dinv[row];
                float4 o = make_float4(acc[r].x * dv, acc[r].y * dv,
                                       acc[r].z * dv, acc[r].w * dv);
                ((float4*)(H + row * M))[cg] = o;
            }
        }
        __syncthreads();
    }
}

// ---------------- pull aggregation: out[d] = b + dinv[d]*(hs[d] + sum hs[src]) ----------------
// one wave per node; R5-proven structure, 8-deep independent gathers for MLP.

template <int M>
__global__ __launch_bounds__(TPB) void agg_pull_kernel(const float* __restrict__ hs,
                                                       const int* __restrict__ csr_src,
                                                       const int* __restrict__ row_ptr,
                                                       const float* __restrict__ dinv,
                                                       const float* __restrict__ bias,
                                                       float* __restrict__ out, int n) {
    const int node = blockIdx.x * (TPB / 64) + (threadIdx.x >> 6);
    const int lane = threadIdx.x & 63;
    if (node >= n) return;
    const int beg = row_ptr[node];
    const int end = row_ptr[node + 1];

    if constexpr (M == 128) {
        const float2* hp = (const float2*)hs;
        float2 a[8];
#pragma unroll
        for (int r = 1; r < 8; ++r) a[r] = make_float2(0.f, 0.f);
        a[0] = hp[(long)node * 64 + lane];  // self-loop term
        for (int base = beg; base < end; base += 64) {
            int m = end - base; if (m > 64) m = 64;
            int idx = (lane < m) ? csr_src[base + lane] : 0;
            int j = 0;
            for (; j + 8 <= m; j += 8) {
#pragma unroll
                for (int r = 0; r < 8; ++r) {
                    int s = __shfl(idx, j + r);
                    float2 v = hp[(long)s * 64 + lane];
                    a[r].x += v.x; a[r].y += v.y;
                }
            }
            for (; j < m; ++j) {
                int s = __shfl(idx, j);
                float2 v = hp[(long)s * 64 + lane];
                a[0].x += v.x; a[0].y += v.y;
            }
        }
#pragma unroll
        for (int r = 4; r < 8; ++r) { a[r - 4].x += a[r].x; a[r - 4].y += a[r].y; }
        float  di = dinv[node];
        float2 bv = ((const float2*)bias)[lane];
        float2 o;
        o.x = bv.x + di * ((a[0].x + a[1].x) + (a[2].x + a[3].x));
        o.y = bv.y + di * ((a[0].y + a[1].y) + (a[2].y + a[3].y));
        ((float2*)out)[(long)node * 64 + lane] = o;
    } else {  // M == 64
        float a[8];
#pragma unroll
        for (int r = 1; r < 8; ++r) a[r] = 0.f;
        a[0] = hs[(long)node * 64 + lane];  // self-loop term
        for (int base = beg; base < end; base += 64) {
            int m = end - base; if (m > 64) m = 64;
            int idx = (lane < m) ? csr_src[base + lane] : 0;
            int j = 0;
            for (; j + 8 <= m; j += 8) {
#pragma unroll
                for (int r = 0; r < 8; ++r) {
                    int s = __shfl(idx, j + r);
                    a[r] += hs[(long)s * 64 + lane];
                }
            }
            for (; j < m; ++j) {
                int s = __shfl(idx, j);
                a[0] += hs[(long)s * 64 + lane];
            }
        }
#pragma unroll
        for (int r = 4; r < 8; ++r) a[r - 4] += a[r];
        float di = dinv[node];
        out[(long)node * 64 + lane] =
            bias[lane] + di * ((a[0] + a[1]) + (a[2] + a[3]));
    }
}

// ---------------- launcher ----------------

extern "C" void kernel_launch(void* const* d_in, const int* in_sizes, int n_in,
                              void* d_out, int out_size, void* d_ws, size_t ws_size,
                              hipStream_t stream) {
    const float* x  = (const float*)d_in[0];
    const int*   ei = (const int*)d_in[1];   // int32 on the wire
    const float* W1 = (const float*)d_in[2];
    const float* b1 = (const float*)d_in[3];
    const float* W2 = (const float*)d_in[4];
    const float* b2 = (const float*)d_in[5];
    float* out = (float*)d_out;

    const int N = in_sizes[0] / 128;   // 100000
    const int E = in_sizes[1] / 2;     // 1600000
    const int* srcv = ei;
    const int* dstv = ei + E;

    const int NBC    = (N + 255) >> CSHIFT;           // 391 coarse buckets
    const int NBLK_E = (E + EPB - 1) / EPB;           // 391 edge blocks
    const int HLEN   = NBC * NBLK_E;                  // 152,881
    const int NCHH   = (HLEN + CHUNK - 1) / CHUNK;    // 150

    // workspace layout (fp32 hs)
    char* p = (char*)d_ws;
    int*   row_ptr    = (int*)p;           p += ((size_t)N + 64) * 4;
    int*   chunk_sums = (int*)p;           p += 1024;
    int*   hist       = (int*)p;           p += ((size_t)HLEN + 64) * 4;
    int*   csr_src    = (int*)p;           p += (size_t)E * 4;
    float* dinv       = (float*)p;         p += ((size_t)N + 64) * 4;
    float* h1         = (float*)p;         p += (size_t)N * 128 * 4;
    float* out1       = (float*)p;         /* p += N*128*4 */
    int2*  pairs      = (int2*)out1;       // alias: out1 dead until after CSR build
    float* h2         = h1;                // h1 dead once out1 complete

    // ---- CSR build + normalization (histogram -> scan -> partition -> finalize) ----
    hist_kernel<<<NBLK_E, 256, 0, stream>>>(dstv, hist, E, NBC, NBLK_E);
    scanA_kernel<<<NCHH, 256, 0, stream>>>(hist, hist, chunk_sums, HLEN);  // in-place safe
    scanB_kernel<<<1, 256, 0, stream>>>(chunk_sums, NCHH);
    scanC_kernel<<<NCHH, 256, 0, stream>>>(hist, chunk_sums, HLEN);
    partition_kernel<<<NBLK_E, 256, 0, stream>>>(srcv, dstv, hist, pairs, E, NBC, NBLK_E);
    bucket_finalize_kernel<<<NBC, 256, 0, stream>>>(pairs, hist, row_ptr, dinv, csr_src,
                                                    N, E, NBC, NBLK_E);

    // ---- layer 1 ----
    gemm_kernel<128, false><<<(N + 31) / 32, TPB, 0, stream>>>(x, W1, dinv, h1, N);
    agg_pull_kernel<128><<<(N + 3) / 4, TPB, 0, stream>>>(h1, csr_src, row_ptr, dinv, b1, out1, N);

    // ---- layer 2 ----
    gemm_kernel<64, true><<<(N + 63) / 64, TPB, 0, stream>>>(out1, W2, dinv, h2, N);
    agg_pull_kernel<64><<<(N + 3) / 4, TPB, 0, stream>>>(h2, csr_src, row_ptr, dinv, b2, out, N);
}

// Round 8
// 387.525 us; speedup vs baseline: 1.9369x; 1.2302x over previous
//
#include <hip/hip_runtime.h>
#include <hip/hip_fp16.h>

#define TPB 256
#define CHUNK 1024   // elements per scan block (256 threads x 4)
#define EPB 4096     // edges per partition block
#define CSHIFT 8     // coarse bucket = 256 nodes

// ---------------- two-level exclusive scan (in-place safe) ----------------

__global__ __launch_bounds__(256) void scanA_kernel(const int* __restrict__ cnt,
                                                    int* __restrict__ row_ptr,
                                                    int* __restrict__ chunk_sums, int n) {
    __shared__ int ls[256];
    const int t    = threadIdx.x;
    const int base = blockIdx.x * CHUNK;
    const int idx  = base + t * 4;
    int4 v = make_int4(0, 0, 0, 0);
    if (idx + 3 < n) v = *(const int4*)(cnt + idx);
    else {
        if (idx + 0 < n) v.x = cnt[idx + 0];
        if (idx + 1 < n) v.y = cnt[idx + 1];
        if (idx + 2 < n) v.z = cnt[idx + 2];
        if (idx + 3 < n) v.w = cnt[idx + 3];
    }
    int s0 = v.x, s1 = s0 + v.y, s2 = s1 + v.z, s3 = s2 + v.w;
    ls[t] = s3;
    __syncthreads();
    for (int off = 1; off < 256; off <<= 1) {
        int xv = (t >= off) ? ls[t - off] : 0;
        __syncthreads();
        ls[t] += xv;
        __syncthreads();
    }
    int excl = (t == 0) ? 0 : ls[t - 1];
    if (idx + 0 < n) row_ptr[idx + 0] = excl;
    if (idx + 1 < n) row_ptr[idx + 1] = excl + s0;
    if (idx + 2 < n) row_ptr[idx + 2] = excl + s1;
    if (idx + 3 < n) row_ptr[idx + 3] = excl + s2;
    if (t == 255) chunk_sums[blockIdx.x] = ls[255];
}

__global__ __launch_bounds__(256) void scanB_kernel(int* __restrict__ chunk_sums, int nch) {
    __shared__ int ls[256];
    const int t = threadIdx.x;
    ls[t] = (t < nch) ? chunk_sums[t] : 0;
    __syncthreads();
    for (int off = 1; off < 256; off <<= 1) {
        int xv = (t >= off) ? ls[t - off] : 0;
        __syncthreads();
        ls[t] += xv;
        __syncthreads();
    }
    if (t < nch) chunk_sums[t] = (t == 0) ? 0 : ls[t - 1];  // exclusive
}

__global__ __launch_bounds__(256) void scanC_kernel(int* __restrict__ row_ptr,
                                                    const int* __restrict__ chunk_sums, int n) {
    const int base = blockIdx.x * CHUNK;
    const int off  = chunk_sums[blockIdx.x];
    for (int k = threadIdx.x; k < CHUNK; k += 256) {
        int i = base + k;
        if (i < n) row_ptr[i] += off;
    }
}

// ---------------- CSR build: deterministic counting partition ----------------

__global__ __launch_bounds__(256) void hist_kernel(const int* __restrict__ dst,
                                                   int* __restrict__ hist_g,
                                                   int e, int nbc, int nblk) {
    __shared__ int hs[512];
    const int t = threadIdx.x;
    for (int i = t; i < nbc; i += 256) hs[i] = 0;
    __syncthreads();
    const int e0  = blockIdx.x * EPB;
    const int lim = min(e0 + EPB, e);
    for (int i = e0 + t; i < lim; i += 256)
        atomicAdd(&hs[dst[i] >> CSHIFT], 1);
    __syncthreads();
    for (int b = t; b < nbc; b += 256)
        hist_g[b * nblk + blockIdx.x] = hs[b];
}

__global__ __launch_bounds__(256) void partition_kernel(const int* __restrict__ src,
                                                        const int* __restrict__ dst,
                                                        const int* __restrict__ hist_scan,
                                                        int2* __restrict__ pairs,
                                                        int e, int nbc, int nblk) {
    __shared__ int  hs[512];
    __shared__ int  lscan[512];
    __shared__ int  lfill[512];
    __shared__ int  base_s[512];
    __shared__ int  ls[256];
    __shared__ int2 sp[EPB];   // 32 KB staging
    const int t = threadIdx.x;
    for (int i = t; i < nbc; i += 256) { hs[i] = 0; lfill[i] = 0; }
    __syncthreads();
    const int e0  = blockIdx.x * EPB;
    const int lim = min(e0 + EPB, e);
    for (int i = e0 + t; i < lim; i += 256)
        atomicAdd(&hs[dst[i] >> CSHIFT], 1);
    __syncthreads();
    int v0 = (2 * t     < nbc) ? hs[2 * t]     : 0;
    int v1 = (2 * t + 1 < nbc) ? hs[2 * t + 1] : 0;
    ls[t] = v0 + v1;
    __syncthreads();
    for (int off = 1; off < 256; off <<= 1) {
        int xv = (t >= off) ? ls[t - off] : 0;
        __syncthreads();
        ls[t] += xv;
        __syncthreads();
    }
    int excl = (t == 0) ? 0 : ls[t - 1];
    if (2 * t     < nbc) lscan[2 * t]     = excl;
    if (2 * t + 1 < nbc) lscan[2 * t + 1] = excl + v0;
    for (int b = t; b < nbc; b += 256) base_s[b] = hist_scan[b * nblk + blockIdx.x];
    __syncthreads();
    for (int i = e0 + t; i < lim; i += 256) {
        int d = dst[i];
        int b = d >> CSHIFT;
        int r = atomicAdd(&lfill[b], 1);
        sp[lscan[b] + r] = make_int2(src[i], d);
    }
    __syncthreads();
    const int cnt = lim - e0;
    for (int i = t; i < cnt; i += 256) {
        int2 pr = sp[i];
        int  b  = pr.y >> CSHIFT;
        pairs[base_s[b] + (i - lscan[b])] = pr;
    }
}

// One block per 256-node bucket: per-node count + scan in LDS, then write
// row_ptr, dinv, and place csr_src. No global atomics anywhere.
__global__ __launch_bounds__(256) void bucket_finalize_kernel(const int2* __restrict__ pairs,
                                                              const int* __restrict__ hist_scan,
                                                              int* __restrict__ row_ptr,
                                                              float* __restrict__ dinv,
                                                              int* __restrict__ csr_src,
                                                              int n, int e, int nbc, int nblk) {
    __shared__ int cnt_s[256];
    __shared__ int fill[256];
    __shared__ int ls[256];
    const int b   = blockIdx.x;
    const int nb0 = b << CSHIFT;
    const int t   = threadIdx.x;
    const int r0  = hist_scan[b * nblk];                       // bucket start
    const int r1  = (b + 1 < nbc) ? hist_scan[(b + 1) * nblk] : e;
    cnt_s[t] = 0;
    __syncthreads();
    for (int i = r0 + t; i < r1; i += 256)
        atomicAdd(&cnt_s[pairs[i].y - nb0], 1);
    __syncthreads();
    int c = cnt_s[t];
    ls[t] = c;
    __syncthreads();
    for (int off = 1; off < 256; off <<= 1) {
        int xv = (t >= off) ? ls[t - off] : 0;
        __syncthreads();
        ls[t] += xv;
        __syncthreads();
    }
    int excl = (t == 0) ? 0 : ls[t - 1];
    int node = nb0 + t;
    if (node < n) {
        row_ptr[node] = r0 + excl;
        dinv[node]    = rsqrtf((float)(c + 1));   // +1 self-loop
    }
    fill[t] = r0 + excl;
    __syncthreads();
    for (int i = r0 + t; i < r1; i += 256) {
        int2 pr = pairs[i];
        int  p  = atomicAdd(&fill[pr.y - nb0], 1);
        csr_src[p] = pr.x;
    }
    if (b == 0 && t == 0) row_ptr[n] = e;
}

// ---------------- dense transform: HS(fp16) = dinv[row] * (relu?)(X) @ W ----------------

template <int M, bool RELU>
__global__ __launch_bounds__(TPB) void gemm_kernel(const float* __restrict__ X,
                                                   const float* __restrict__ W,
                                                   const float* __restrict__ dinv,
                                                   __half* __restrict__ H, int nrows) {
    constexpr int CG  = M / 4;
    constexpr int RG  = TPB / CG;
    constexpr int R   = 4;
    constexpr int RPB = RG * R;
    __shared__ float Wl[128 * M];
    __shared__ float Xl[RPB * 128];

    for (int i = threadIdx.x; i < 128 * M / 4; i += TPB)
        ((float4*)Wl)[i] = ((const float4*)W)[i];

    const int cg = threadIdx.x % CG;
    const int rg = threadIdx.x / CG;

    for (long row0 = (long)blockIdx.x * RPB; row0 < nrows; row0 += (long)gridDim.x * RPB) {
        for (int f = threadIdx.x; f < RPB * 32; f += TPB) {
            int  r   = f >> 5;
            int  c4  = f & 31;
            long row = row0 + r;
            float4 v = make_float4(0.f, 0.f, 0.f, 0.f);
            if (row < nrows) v = ((const float4*)(X + row * 128))[c4];
            if (RELU) {
                v.x = fmaxf(v.x, 0.f); v.y = fmaxf(v.y, 0.f);
                v.z = fmaxf(v.z, 0.f); v.w = fmaxf(v.w, 0.f);
            }
            ((float4*)Xl)[f] = v;
        }
        __syncthreads();

        float4 acc[R];
#pragma unroll
        for (int r = 0; r < R; ++r) acc[r] = make_float4(0.f, 0.f, 0.f, 0.f);
        const float* xb = Xl + (rg * R) * 128;

#pragma unroll 8
        for (int k = 0; k < 128; ++k) {
            float4 wv = ((const float4*)Wl)[k * CG + cg];
#pragma unroll
            for (int r = 0; r < R; ++r) {
                float xv = xb[r * 128 + k];
                acc[r].x += xv * wv.x; acc[r].y += xv * wv.y;
                acc[r].z += xv * wv.z; acc[r].w += xv * wv.w;
            }
        }

#pragma unroll
        for (int r = 0; r < R; ++r) {
            long row = row0 + rg * R + r;
            if (row < nrows) {
                float dv = dinv[row];
                __half2 p0 = __floats2half2_rn(acc[r].x * dv, acc[r].y * dv);
                __half2 p1 = __floats2half2_rn(acc[r].z * dv, acc[r].w * dv);
                uint2 pk;
                pk.x = *reinterpret_cast<unsigned int*>(&p0);
                pk.y = *reinterpret_cast<unsigned int*>(&p1);
                ((uint2*)(H + row * M))[cg] = pk;
            }
        }
        __syncthreads();
    }
}

// ---------------- pull aggregation: out[d] = b + dinv[d]*(hs[d] + sum hs[src]) ----------------
// R7-proven loop structure; only the hs element type changed to fp16.
// M=128: lane loads __half2 (cols 2*lane, 2*lane+1). M=64: lane loads __half (col lane).

template <int M>
__global__ __launch_bounds__(TPB) void agg_pull_kernel(const __half* __restrict__ hs,
                                                       const int* __restrict__ csr_src,
                                                       const int* __restrict__ row_ptr,
                                                       const float* __restrict__ dinv,
                                                       const float* __restrict__ bias,
                                                       float* __restrict__ out, int n) {
    const int node = blockIdx.x * (TPB / 64) + (threadIdx.x >> 6);
    const int lane = threadIdx.x & 63;
    if (node >= n) return;
    const int beg = row_ptr[node];
    const int end = row_ptr[node + 1];

    if constexpr (M == 128) {
        const __half2* hp = (const __half2*)hs;
        float2 a[8];
#pragma unroll
        for (int r = 1; r < 8; ++r) a[r] = make_float2(0.f, 0.f);
        a[0] = __half22float2(hp[(long)node * 64 + lane]);  // self-loop term
        for (int base = beg; base < end; base += 64) {
            int m = end - base; if (m > 64) m = 64;
            int idx = (lane < m) ? csr_src[base + lane] : 0;
            int j = 0;
            for (; j + 8 <= m; j += 8) {
#pragma unroll
                for (int r = 0; r < 8; ++r) {
                    int s = __shfl(idx, j + r);
                    float2 v = __half22float2(hp[(long)s * 64 + lane]);
                    a[r].x += v.x; a[r].y += v.y;
                }
            }
            for (; j < m; ++j) {
                int s = __shfl(idx, j);
                float2 v = __half22float2(hp[(long)s * 64 + lane]);
                a[0].x += v.x; a[0].y += v.y;
            }
        }
#pragma unroll
        for (int r = 4; r < 8; ++r) { a[r - 4].x += a[r].x; a[r - 4].y += a[r].y; }
        float  di = dinv[node];
        float2 bv = ((const float2*)bias)[lane];
        float2 o;
        o.x = bv.x + di * ((a[0].x + a[1].x) + (a[2].x + a[3].x));
        o.y = bv.y + di * ((a[0].y + a[1].y) + (a[2].y + a[3].y));
        ((float2*)out)[(long)node * 64 + lane] = o;
    } else {  // M == 64
        float a[8];
#pragma unroll
        for (int r = 1; r < 8; ++r) a[r] = 0.f;
        a[0] = __half2float(hs[(long)node * 64 + lane]);  // self-loop term
        for (int base = beg; base < end; base += 64) {
            int m = end - base; if (m > 64) m = 64;
            int idx = (lane < m) ? csr_src[base + lane] : 0;
            int j = 0;
            for (; j + 8 <= m; j += 8) {
#pragma unroll
                for (int r = 0; r < 8; ++r) {
                    int s = __shfl(idx, j + r);
                    a[r] += __half2float(hs[(long)s * 64 + lane]);
                }
            }
            for (; j < m; ++j) {
                int s = __shfl(idx, j);
                a[0] += __half2float(hs[(long)s * 64 + lane]);
            }
        }
#pragma unroll
        for (int r = 4; r < 8; ++r) a[r - 4] += a[r];
        float di = dinv[node];
        out[(long)node * 64 + lane] =
            bias[lane] + di * ((a[0] + a[1]) + (a[2] + a[3]));
    }
}

// ---------------- launcher ----------------

extern "C" void kernel_launch(void* const* d_in, const int* in_sizes, int n_in,
                              void* d_out, int out_size, void* d_ws, size_t ws_size,
                              hipStream_t stream) {
    const float* x  = (const float*)d_in[0];
    const int*   ei = (const int*)d_in[1];   // int32 on the wire
    const float* W1 = (const float*)d_in[2];
    const float* b1 = (const float*)d_in[3];
    const float* W2 = (const float*)d_in[4];
    const float* b2 = (const float*)d_in[5];
    float* out = (float*)d_out;

    const int N = in_sizes[0] / 128;   // 100000
    const int E = in_sizes[1] / 2;     // 1600000
    const int* srcv = ei;
    const int* dstv = ei + E;

    const int NBC    = (N + 255) >> CSHIFT;           // 391 coarse buckets
    const int NBLK_E = (E + EPB - 1) / EPB;           // 391 edge blocks
    const int HLEN   = NBC * NBLK_E;                  // 152,881
    const int NCHH   = (HLEN + CHUNK - 1) / CHUNK;    // 150

    // workspace layout
    char* p = (char*)d_ws;
    int*    row_ptr    = (int*)p;           p += ((size_t)N + 64) * 4;
    int*    chunk_sums = (int*)p;           p += 1024;
    int*    hist       = (int*)p;           p += ((size_t)HLEN + 64) * 4;
    int*    csr_src    = (int*)p;           p += (size_t)E * 4;
    float*  dinv       = (float*)p;         p += ((size_t)N + 64) * 4;
    __half* hs1        = (__half*)p;        p += (size_t)N * 128 * 2;
    float*  out1       = (float*)p;         p += (size_t)N * 128 * 4;
    int2*   pairs      = (int2*)out1;       // alias: out1 dead until after CSR build
    __half* hs2        = hs1;               // hs1 dead once out1 complete

    // ---- CSR build + normalization (histogram -> scan -> partition -> finalize) ----
    hist_kernel<<<NBLK_E, 256, 0, stream>>>(dstv, hist, E, NBC, NBLK_E);
    scanA_kernel<<<NCHH, 256, 0, stream>>>(hist, hist, chunk_sums, HLEN);  // in-place safe
    scanB_kernel<<<1, 256, 0, stream>>>(chunk_sums, NCHH);
    scanC_kernel<<<NCHH, 256, 0, stream>>>(hist, chunk_sums, HLEN);
    partition_kernel<<<NBLK_E, 256, 0, stream>>>(srcv, dstv, hist, pairs, E, NBC, NBLK_E);
    bucket_finalize_kernel<<<NBC, 256, 0, stream>>>(pairs, hist, row_ptr, dinv, csr_src,
                                                    N, E, NBC, NBLK_E);

    // ---- layer 1 ----
    gemm_kernel<128, false><<<(N + 31) / 32, TPB, 0, stream>>>(x, W1, dinv, hs1, N);
    agg_pull_kernel<128><<<(N + 3) / 4, TPB, 0, stream>>>(hs1, csr_src, row_ptr, dinv, b1, out1, N);

    // ---- layer 2 ----
    gemm_kernel<64, true><<<(N + 63) / 64, TPB, 0, stream>>>(out1, W2, dinv, hs2, N);
    agg_pull_kernel<64><<<(N + 3) / 4, TPB, 0, stream>>>(hs2, csr_src, row_ptr, dinv, b2, out, N);
}